// Round 5
// baseline (191.025 us; speedup 1.0000x reference)
//
#include <hip/hip_runtime.h>

#define SL 256
#define RSTRIDE 312   // R-copy stride: >=302 (causal s0<=294 +8), mult of 8,
                      // 156 words -> copy bank offsets c*28 mod 32 all distinct

typedef _Float16 f16;
typedef _Float16 f16x8 __attribute__((ext_vector_type(8)));
typedef _Float16 f16x4 __attribute__((ext_vector_type(4)));
typedef float f32x4 __attribute__((ext_vector_type(4)));

// ---------------------------------------------------------------------------
// Filter MLP: one block per (l, sel); sel=0 -> X params, sel=1 -> Y params.
// Writes transposed f16 filters hT[sel][d][l] for fast R-table builds.
// ---------------------------------------------------------------------------
__global__ __launch_bounds__(64) void k_filters(
    const float* __restrict__ z,
    const float* __restrict__ Xw1, const float* __restrict__ Xb1,
    const float* __restrict__ Xw2, const float* __restrict__ Xb2,
    const float* __restrict__ Xw3, const float* __restrict__ Xb3,
    const float* __restrict__ Xwo, const float* __restrict__ Xfreq,
    const float* __restrict__ Yw1, const float* __restrict__ Yb1,
    const float* __restrict__ Yw2, const float* __restrict__ Yb2,
    const float* __restrict__ Yw3, const float* __restrict__ Yb3,
    const float* __restrict__ Ywo, const float* __restrict__ Yfreq,
    f16* __restrict__ hxT, f16* __restrict__ hyT)
{
    const int l = blockIdx.x;
    const int sel = blockIdx.y;
    const int t = threadIdx.x;
    const float* w1 = sel ? Yw1 : Xw1;  const float* b1 = sel ? Yb1 : Xb1;
    const float* w2 = sel ? Yw2 : Xw2;  const float* b2 = sel ? Yb2 : Xb2;
    const float* w3 = sel ? Yw3 : Xw3;  const float* b3 = sel ? Yb3 : Xb3;
    const float* wo = sel ? Ywo : Xwo;  const float* freq = sel ? Yfreq : Xfreq;
    f16* hT = sel ? hyT : hxT;

    __shared__ float zb[33];
    __shared__ float ha[64];
    __shared__ float hb[64];

    if (t < 33) zb[t] = z[l * 33 + t];
    __syncthreads();

    const float fr = freq[t];
    float s = b1[t];
    for (int k = 0; k < 33; ++k) s += zb[k] * w1[k * 64 + t];
    ha[t] = sinf(fr * s);
    __syncthreads();

    s = b2[t];
    for (int k = 0; k < 64; ++k) s += ha[k] * w2[k * 64 + t];
    hb[t] = sinf(fr * s);
    __syncthreads();

    s = b3[t];
    for (int k = 0; k < 64; ++k) s += hb[k] * w3[k * 64 + t];
    ha[t] = sinf(fr * s);
    __syncthreads();

    s = 0.f;
    for (int k = 0; k < 64; ++k) s += ha[k] * wo[k * 64 + t];

    const float MIN_DEC = -3.0701134573253937f;   // log(0.01)/1.5
    const float MAX_DEC = -15.350567286626968f;   // log(0.01)/0.3
    float ad = fabsf(MIN_DEC + (MAX_DEC - MIN_DEC) * ((float)t / 63.0f));
    float tl = (float)l / 255.0f;
    hT[t * 256 + l] = (f16)(s * expf(-tl * ad));   // [d][l]
}

__device__ __forceinline__ f16x8 cvt8(float4 a, float4 b)
{
    f16x8 h;
    h[0] = (f16)a.x; h[1] = (f16)a.y; h[2] = (f16)a.z; h[3] = (f16)a.w;
    h[4] = (f16)b.x; h[5] = (f16)b.y; h[6] = (f16)b.z; h[7] = (f16)b.w;
    return h;
}

// ---------------------------------------------------------------------------
// R-copy Toeplitz table: 8 shift-staggered copies of reversed zero-padded
// filter column so every Toeplitz fragment is one aligned ds_read_b128.
//   Rfull[u] = (u<=255) ? h[255-u] : 0 ;  R[c*RSTRIDE+k] = Rfull[k+c]
// Fragment T[row][k] = h[row-k] = Rfull[255-row+k]:
//   s0 = 255-row+k0 ; c = s0&7 ; f16x8 at R[c*RSTRIDE + (s0-c)]
// ---------------------------------------------------------------------------
__device__ __forceinline__ void build_R(f16* R, const f16* __restrict__ hc,
                                        int tid)
{
    for (int idx = tid; idx < 8 * RSTRIDE; idx += 512) {
        int c = idx / RSTRIDE;
        int k = idx - c * RSTRIDE;
        int u = k + c;
        R[idx] = (u <= 255) ? hc[255 - u] : (f16)0.f;
    }
}

// ---------------------------------------------------------------------------
// Phase 1 (templated on J0 so all causality skips constant-fold):
//   M[p][jl] = sum_q x[p][q]*hy[J0+jl-q].  hy[j-q]=0 for q>j, so j-tile c8
//   at K-step s is all-zero when 32s > J0+16c8+15 -> skip bf read + MFMAs.
// ---------------------------------------------------------------------------
template<int J0>
__device__ __forceinline__ void phase1(
    const float* __restrict__ xr0, const float* __restrict__ xr1,
    const f16* __restrict__ R, f32x4 (&acc)[16], int ln, int quad)
{
    constexpr int QS = (J0 == 0) ? 4 : 8;   // q < J0+128 needed
    float4 a0 = *(const float4*)xr0;
    float4 a1 = *(const float4*)(xr0 + 4);
    float4 b0 = *(const float4*)xr1;
    float4 b1 = *(const float4*)(xr1 + 4);

#pragma unroll
    for (int s = 0; s < QS; ++s) {
        const int q0 = s * 32;
        f16x8 af0 = cvt8(a0, a1);
        f16x8 af1 = cvt8(b0, b1);
        if (s + 1 < QS) {
            a0 = *(const float4*)(xr0 + q0 + 32);
            a1 = *(const float4*)(xr0 + q0 + 36);
            b0 = *(const float4*)(xr1 + q0 + 32);
            b1 = *(const float4*)(xr1 + q0 + 36);
        }
#pragma unroll
        for (int c8 = 0; c8 < 8; ++c8) {
            if (32 * s <= J0 + c8 * 16 + 15) {     // compile-time fold
                int j = J0 + c8 * 16 + ln;
                int s0 = 255 - j + q0 + quad * 8;
                int c = s0 & 7;
                f16x8 bf = *(const f16x8*)&R[c * RSTRIDE + (s0 - c)];
                acc[c8] = __builtin_amdgcn_mfma_f32_16x16x32_f16(
                    af0, bf, acc[c8], 0, 0, 0);
                acc[8 + c8] = __builtin_amdgcn_mfma_f32_16x16x32_f16(
                    af1, bf, acc[8 + c8], 0, 0, 0);
            }
        }
    }
}

// ---------------------------------------------------------------------------
// SPLIT PATH kernel 1: pure-streaming producer.  grid 512 (bd, j-half),
// 512 threads, LDS = 5 KB (Ry only).  Identical math to the fused phase 1
// but M goes to a 32 MB global buffer [bd][j][p] f16.  HBM: fetch x 64 MB +
// write M 32 MB, streamed continuously (no mid-kernel barrier separates
// HBM phases -> high duty cycle).
// ---------------------------------------------------------------------------
__global__ __launch_bounds__(512, 4) void k_conv1(
    const float* __restrict__ x, const f16* __restrict__ hyT,
    f16* __restrict__ M)
{
    const int bd = blockIdx.x & 255;
    const int j0 = (blockIdx.x >> 8) << 7;  // 0 or 128
    const int d  = bd & 63;
    const int tid  = threadIdx.x;
    const int lane = tid & 63;
    const int wave = tid >> 6;
    const int ln   = lane & 15;
    const int quad = lane >> 4;

    __shared__ __align__(16) f16 Ry[8 * RSTRIDE];
    build_R(Ry, hyT + d * 256, tid);

    f32x4 acc[16];
#pragma unroll
    for (int a = 0; a < 16; ++a) acc[a] = (f32x4){0.f, 0.f, 0.f, 0.f};

    __syncthreads();   // Ry ready

    const float* xr0 = x + (size_t)bd * (SL * SL) + (wave * 32 + ln) * SL + quad * 8;
    const float* xr1 = xr0 + 16 * SL;
    if (j0 == 0) phase1<0>(xr0, xr1, Ry, acc, ln, quad);
    else         phase1<128>(xr0, xr1, Ry, acc, ln, quad);

    // store M[bd][jl][pb..pb+3] f16x4
    f16* Mb = M + (size_t)bd * (SL * SL);
#pragma unroll
    for (int r = 0; r < 2; ++r)
#pragma unroll
        for (int c8 = 0; c8 < 8; ++c8) {
            int jl = j0 + c8 * 16 + ln;
            int pb = wave * 32 + r * 16 + quad * 4;
            f32x4 a = acc[r * 8 + c8];
            f16x4 v;
            v[0] = (f16)a[0]; v[1] = (f16)a[1];
            v[2] = (f16)a[2]; v[3] = (f16)a[3];
            *(f16x4*)&Mb[jl * 256 + pb] = v;
        }
}

// ---------------------------------------------------------------------------
// SPLIT PATH kernel 2: pure-streaming consumer.  grid 512 (bd, j-half),
// 512 threads, LDS = 5 KB (Rx only).  D[jl][i] = sum_p M[jl][p]*hx[i-p];
// M reads are L2/L3-hot (32 MB, working set < L3).  Wave (igrp,jgrp) owns
// i-tiles 4igrp..4igrp+3 x 64 j-rows; causal p-steps nst = 2(igrp+1) with
// per-ct skip (p0 <= igrp*64+ct*16+15).  Epilogue identical to fused R2:
// out[i][j..j+3] = D/512 + x*bias, float4.  HBM: write out 64 MB streamed.
// ---------------------------------------------------------------------------
__global__ __launch_bounds__(512, 4) void k_conv2(
    const float* __restrict__ x, const f16* __restrict__ M,
    const f16* __restrict__ hxT, const float* __restrict__ bias,
    float* __restrict__ out)
{
    const int bd = blockIdx.x & 255;
    const int jh = blockIdx.x >> 8;         // j-half
    const int d  = bd & 63;
    const int tid  = threadIdx.x;
    const int lane = tid & 63;
    const int wave = tid >> 6;
    const int ln   = lane & 15;
    const int quad = lane >> 4;

    __shared__ __align__(16) f16 Rx[8 * RSTRIDE];
    build_R(Rx, hxT + d * 256, tid);

    f32x4 acc[16];
#pragma unroll
    for (int a = 0; a < 16; ++a) acc[a] = (f32x4){0.f, 0.f, 0.f, 0.f};

    __syncthreads();   // Rx ready

    const int igrp = wave & 3;
    const int jgrp = wave >> 2;
    const f16* Mb = M + (size_t)bd * (SL * SL) + (size_t)(jh * 128 + jgrp * 64) * 256;
    const int nst = (igrp + 1) * 2;          // causal p-step bound

    for (int s = 0; s < nst; ++s) {
        const int p0 = s * 32;
        f16x8 af[4];
#pragma unroll
        for (int rt = 0; rt < 4; ++rt)        // A = M[jl][p], coalesced 16B/ln
            af[rt] = *(const f16x8*)&Mb[(rt * 16 + ln) * 256 + p0 + quad * 8];
#pragma unroll
        for (int ct = 0; ct < 4; ++ct) {      // B[p][i] = hx[i-p]
            if (p0 <= igrp * 64 + ct * 16 + 15) { // wave-uniform causal skip
                int i = igrp * 64 + ct * 16 + ln;
                int s0 = 255 - i + p0 + quad * 8;
                int c = s0 & 7;
                f16x8 bf = *(const f16x8*)&Rx[c * RSTRIDE + (s0 - c)];
#pragma unroll
                for (int rt = 0; rt < 4; ++rt)
                    acc[rt * 4 + ct] = __builtin_amdgcn_mfma_f32_16x16x32_f16(
                        af[rt], bf, acc[rt * 4 + ct], 0, 0, 0);
            }
        }
    }

    // epilogue: out[i][j..j+3] = acc/512 + x*bias  (float4, coalesced)
    const float bv = bias[d];
    const float sc = 1.0f / 512.0f;
    const float* xbd = x + (size_t)bd * (SL * SL);
    float* obd = out + (size_t)bd * (SL * SL);
#pragma unroll
    for (int rt = 0; rt < 4; ++rt)
#pragma unroll
        for (int ct = 0; ct < 4; ++ct) {
            int i = igrp * 64 + ct * 16 + ln;
            int j = jh * 128 + jgrp * 64 + rt * 16 + quad * 4;
            f32x4 a = acc[rt * 4 + ct];
            float4 xv = *(const float4*)(xbd + i * SL + j);
            float4 o;
            o.x = a[0] * sc + xv.x * bv;
            o.y = a[1] * sc + xv.y * bv;
            o.z = a[2] * sc + xv.z * bv;
            o.w = a[3] * sc + xv.w * bv;
            *(float4*)(obd + i * SL + j) = o;
        }
}

// ---------------------------------------------------------------------------
// FALLBACK (small workspace): the round-2 fused kernel (best fused variant,
// 46.3 us): LDS tmp + two build_R phases.
// ---------------------------------------------------------------------------
__global__ __launch_bounds__(512, 4) void k_fused(
    const float* __restrict__ x, const f16* __restrict__ hxT,
    const f16* __restrict__ hyT, const float* __restrict__ bias,
    float* __restrict__ out)
{
    const int bd = blockIdx.x & 255;
    const int j0 = (blockIdx.x >> 8) << 7;
    const int d  = bd & 63;
    const int tid  = threadIdx.x;
    const int lane = tid & 63;
    const int wave = tid >> 6;
    const int ln   = lane & 15;
    const int quad = lane >> 4;

    __shared__ __align__(16) f16 tmp[128 * 256];   // [jl][p ^ ((jl&7)<<3)]
    __shared__ __align__(16) f16 R[8 * RSTRIDE];

    const float* xbd = x + (size_t)bd * (SL * SL);

    build_R(R, hyT + d * 256, tid);

    f32x4 acc[16];
#pragma unroll
    for (int a = 0; a < 16; ++a) acc[a] = (f32x4){0.f, 0.f, 0.f, 0.f};

    __syncthreads();   // R(hy) ready

    {
        const float* xr0 = xbd + (wave * 32 + ln) * SL + quad * 8;
        const float* xr1 = xr0 + 16 * SL;
        if (j0 == 0) phase1<0>(xr0, xr1, R, acc, ln, quad);
        else         phase1<128>(xr0, xr1, R, acc, ln, quad);

#pragma unroll
        for (int r = 0; r < 2; ++r)
#pragma unroll
            for (int c8 = 0; c8 < 8; ++c8) {
                int jl = c8 * 16 + ln;
                int pb = wave * 32 + r * 16 + quad * 4;
                f32x4 a = acc[r * 8 + c8];
                f16x4 v;
                v[0] = (f16)a[0]; v[1] = (f16)a[1];
                v[2] = (f16)a[2]; v[3] = (f16)a[3];
                *(f16x4*)&tmp[jl * 256 + (pb ^ ((jl & 7) << 3))] = v;
            }
    }

    __syncthreads();   // tmp complete, R(hy) reads done
    build_R(R, hxT + d * 256, tid);
#pragma unroll
    for (int a = 0; a < 16; ++a) acc[a] = (f32x4){0.f, 0.f, 0.f, 0.f};
    __syncthreads();   // R(hx) ready

    const int igrp = wave & 3;
    const int jgrp = wave >> 2;
    const int nst = (igrp + 1) * 2;
    for (int s = 0; s < nst; ++s) {
        const int p0 = s * 32;
        f16x8 af[4];
#pragma unroll
        for (int rt = 0; rt < 4; ++rt) {
            int jl = jgrp * 64 + rt * 16 + ln;
            int off = (p0 + quad * 8) ^ ((jl & 7) << 3);
            af[rt] = *(const f16x8*)&tmp[jl * 256 + off];
        }
#pragma unroll
        for (int ct = 0; ct < 4; ++ct) {
            if (p0 <= igrp * 64 + ct * 16 + 15) {
                int i = igrp * 64 + ct * 16 + ln;
                int s0 = 255 - i + p0 + quad * 8;
                int c = s0 & 7;
                f16x8 bf = *(const f16x8*)&R[c * RSTRIDE + (s0 - c)];
#pragma unroll
                for (int rt = 0; rt < 4; ++rt)
                    acc[rt * 4 + ct] = __builtin_amdgcn_mfma_f32_16x16x32_f16(
                        af[rt], bf, acc[rt * 4 + ct], 0, 0, 0);
            }
        }
    }

    const float bv = bias[d];
    const float sc = 1.0f / 512.0f;
    float* obd = out + (size_t)bd * (SL * SL);
#pragma unroll
    for (int rt = 0; rt < 4; ++rt)
#pragma unroll
        for (int ct = 0; ct < 4; ++ct) {
            int i = igrp * 64 + ct * 16 + ln;
            int j = j0 + jgrp * 64 + rt * 16 + quad * 4;
            f32x4 a = acc[rt * 4 + ct];
            float4 xv = *(const float4*)(xbd + i * SL + j);
            float4 o;
            o.x = a[0] * sc + xv.x * bv;
            o.y = a[1] * sc + xv.y * bv;
            o.z = a[2] * sc + xv.z * bv;
            o.w = a[3] * sc + xv.w * bv;
            *(float4*)(obd + i * SL + j) = o;
        }
}

extern "C" void kernel_launch(void* const* d_in, const int* in_sizes, int n_in,
                              void* d_out, int out_size, void* d_ws, size_t ws_size,
                              hipStream_t stream)
{
    (void)in_sizes; (void)n_in; (void)out_size;
    const float* x     = (const float*)d_in[0];
    const float* z     = (const float*)d_in[1];
    const float* Xw1   = (const float*)d_in[2];
    const float* Xb1   = (const float*)d_in[3];
    const float* Xw2   = (const float*)d_in[4];
    const float* Xb2   = (const float*)d_in[5];
    const float* Xw3   = (const float*)d_in[6];
    const float* Xb3   = (const float*)d_in[7];
    const float* Xwo   = (const float*)d_in[8];
    const float* Xfreq = (const float*)d_in[9];
    const float* Yw1   = (const float*)d_in[10];
    const float* Yb1   = (const float*)d_in[11];
    const float* Yw2   = (const float*)d_in[12];
    const float* Yb2   = (const float*)d_in[13];
    const float* Yw3   = (const float*)d_in[14];
    const float* Yb3   = (const float*)d_in[15];
    const float* Ywo   = (const float*)d_in[16];
    const float* Yfreq = (const float*)d_in[17];
    const float* bias  = (const float*)d_in[18];

    f16* hxT = (f16*)d_ws;                 // [64][256] f16
    f16* hyT = hxT + 64 * 256;             // [64][256] f16
    const size_t filt_bytes = 2u * 64 * 256 * sizeof(f16);       // 64 KB
    const size_t M_bytes    = (size_t)256 * 256 * 256 * sizeof(f16); // 32 MB

    k_filters<<<dim3(256, 2), 64, 0, stream>>>(
        z, Xw1, Xb1, Xw2, Xb2, Xw3, Xb3, Xwo, Xfreq,
        Yw1, Yb1, Yw2, Yb2, Yw3, Yb3, Ywo, Yfreq, hxT, hyT);

    if (ws_size >= filt_bytes + M_bytes) {
        f16* M = (f16*)((char*)d_ws + filt_bytes);   // [bd][j][p] f16
        k_conv1<<<512, 512, 0, stream>>>(x, hyT, M);
        k_conv2<<<512, 512, 0, stream>>>(x, M, hxT, bias, (float*)d_out);
    } else {
        k_fused<<<512, 512, 0, stream>>>(x, hxT, hyT, bias, (float*)d_out);
    }
}

// Round 6
// 166.766 us; speedup vs baseline: 1.1455x; 1.1455x over previous
//
#include <hip/hip_runtime.h>

#define SL 256
#define RSTRIDE 312   // R-copy stride: >=302 (causal s0<=294 +8), mult of 8,
                      // 156 words -> copy bank offsets c*28 mod 32 all distinct

typedef _Float16 f16;
typedef _Float16 f16x8 __attribute__((ext_vector_type(8)));
typedef _Float16 f16x4 __attribute__((ext_vector_type(4)));
typedef float f32x4 __attribute__((ext_vector_type(4)));

// ---------------------------------------------------------------------------
// Filter MLP: one block per (l, sel); sel=0 -> X params, sel=1 -> Y params.
// Writes transposed f16 filters hT[sel][d][l] for fast R-table builds.
// ---------------------------------------------------------------------------
__global__ __launch_bounds__(64) void k_filters(
    const float* __restrict__ z,
    const float* __restrict__ Xw1, const float* __restrict__ Xb1,
    const float* __restrict__ Xw2, const float* __restrict__ Xb2,
    const float* __restrict__ Xw3, const float* __restrict__ Xb3,
    const float* __restrict__ Xwo, const float* __restrict__ Xfreq,
    const float* __restrict__ Yw1, const float* __restrict__ Yb1,
    const float* __restrict__ Yw2, const float* __restrict__ Yb2,
    const float* __restrict__ Yw3, const float* __restrict__ Yb3,
    const float* __restrict__ Ywo, const float* __restrict__ Yfreq,
    f16* __restrict__ hxT, f16* __restrict__ hyT)
{
    const int l = blockIdx.x;
    const int sel = blockIdx.y;
    const int t = threadIdx.x;
    const float* w1 = sel ? Yw1 : Xw1;  const float* b1 = sel ? Yb1 : Xb1;
    const float* w2 = sel ? Yw2 : Xw2;  const float* b2 = sel ? Yb2 : Xb2;
    const float* w3 = sel ? Yw3 : Xw3;  const float* b3 = sel ? Yb3 : Xb3;
    const float* wo = sel ? Ywo : Xwo;  const float* freq = sel ? Yfreq : Xfreq;
    f16* hT = sel ? hyT : hxT;

    __shared__ float zb[33];
    __shared__ float ha[64];
    __shared__ float hb[64];

    if (t < 33) zb[t] = z[l * 33 + t];
    __syncthreads();

    const float fr = freq[t];
    float s = b1[t];
    for (int k = 0; k < 33; ++k) s += zb[k] * w1[k * 64 + t];
    ha[t] = sinf(fr * s);
    __syncthreads();

    s = b2[t];
    for (int k = 0; k < 64; ++k) s += ha[k] * w2[k * 64 + t];
    hb[t] = sinf(fr * s);
    __syncthreads();

    s = b3[t];
    for (int k = 0; k < 64; ++k) s += hb[k] * w3[k * 64 + t];
    ha[t] = sinf(fr * s);
    __syncthreads();

    s = 0.f;
    for (int k = 0; k < 64; ++k) s += ha[k] * wo[k * 64 + t];

    const float MIN_DEC = -3.0701134573253937f;   // log(0.01)/1.5
    const float MAX_DEC = -15.350567286626968f;   // log(0.01)/0.3
    float ad = fabsf(MIN_DEC + (MAX_DEC - MIN_DEC) * ((float)t / 63.0f));
    float tl = (float)l / 255.0f;
    hT[t * 256 + l] = (f16)(s * expf(-tl * ad));   // [d][l]
}

__device__ __forceinline__ f16x8 cvt8(float4 a, float4 b)
{
    f16x8 h;
    h[0] = (f16)a.x; h[1] = (f16)a.y; h[2] = (f16)a.z; h[3] = (f16)a.w;
    h[4] = (f16)b.x; h[5] = (f16)b.y; h[6] = (f16)b.z; h[7] = (f16)b.w;
    return h;
}

// ---------------------------------------------------------------------------
// R-copy Toeplitz table: 8 shift-staggered copies of reversed zero-padded
// filter column so every Toeplitz fragment is one aligned ds_read_b128.
//   Rfull[u] = (u<=255) ? h[255-u] : 0 ;  R[c*RSTRIDE+k] = Rfull[k+c]
// Fragment T[row][k] = h[row-k] = Rfull[255-row+k]:
//   s0 = 255-row+k0 ; c = s0&7 ; f16x8 at R[c*RSTRIDE + (s0-c)]
// ---------------------------------------------------------------------------
template<int NT>
__device__ __forceinline__ void build_R(f16* R, const f16* __restrict__ hc,
                                        int tid)
{
    for (int idx = tid; idx < 8 * RSTRIDE; idx += NT) {
        int c = idx / RSTRIDE;
        int k = idx - c * RSTRIDE;
        int u = k + c;
        R[idx] = (u <= 255) ? hc[255 - u] : (f16)0.f;
    }
}

// ---------------------------------------------------------------------------
// ONE-BLOCK-PER-BD kernel: grid 256 x 1024 threads (16 waves = 16 waves/CU,
// exactly one block per CU).  Dynamic LDS 137.8 KB: full M tmp [256j][256p]
// (128 KB, XOR-swizzled) + Ry + Rx.  vs the j-split fused kernel this
// (a) fetches x exactly once (no half-0/half-1 duplicate reads),
// (b) has zero block-class imbalance (every block identical work),
// (c) phase-1 waves are register-lighter (16 rows -> 2 float4 in flight).
// Math is bit-identical to the j-split version (same tiles/order/rounding).
//
// Phase 1: wave w owns p-rows [16w,16w+16), all 16 j-tiles; causal skip:
//   tile c8 at q-step s active iff 32s <= 16*c8+15 (72 of 128 survive).
// Phase 2: wave = 4(igrp) x 4(jgrp); D[jl][i] = sum_p tmp[jl][p]*hx[i-p];
//   causal p-steps nst=2(igrp+1), per-ct skip p0 <= igrp*64+ct*16+15.
// Epilogue: out[i][j..j+3] = D/512 + x*bias (float4, x read L2-hot).
// ---------------------------------------------------------------------------
__global__ __launch_bounds__(1024, 4) void k_one(
    const float* __restrict__ x, const f16* __restrict__ hxT,
    const f16* __restrict__ hyT, const float* __restrict__ bias,
    float* __restrict__ out)
{
    extern __shared__ __align__(16) f16 smem[];
    f16* tmp = smem;                    // [jl][p ^ ((jl&7)<<3)]  256x256
    f16* Ry  = smem + 256 * 256;        // 8*RSTRIDE
    f16* Rx  = Ry + 8 * RSTRIDE;        // 8*RSTRIDE

    const int bd = blockIdx.x;          // b*64 + d
    const int d  = bd & 63;
    const int tid  = threadIdx.x;
    const int lane = tid & 63;
    const int wave = tid >> 6;          // 0..15
    const int ln   = lane & 15;
    const int quad = lane >> 4;

    const float* xbd = x + (size_t)bd * (SL * SL);

    build_R<1024>(Ry, hyT + d * 256, tid);

    f32x4 acc[16];
#pragma unroll
    for (int a = 0; a < 16; ++a) acc[a] = (f32x4){0.f, 0.f, 0.f, 0.f};

    __syncthreads();   // Ry ready

    // ---------------- Phase 1: wave owns p-rows [wave*16, wave*16+16) ------
    {
        const float* xr = xbd + (wave * 16 + ln) * SL + quad * 8;
        float4 a0 = *(const float4*)xr;
        float4 a1 = *(const float4*)(xr + 4);

#pragma unroll
        for (int s = 0; s < 8; ++s) {
            const int q0 = s * 32;
            f16x8 af = cvt8(a0, a1);
            if (s + 1 < 8) {
                a0 = *(const float4*)(xr + q0 + 32);
                a1 = *(const float4*)(xr + q0 + 36);
            }
#pragma unroll
            for (int c8 = 0; c8 < 16; ++c8) {
                if (32 * s <= c8 * 16 + 15) {      // compile-time fold
                    int j = c8 * 16 + ln;
                    int s0 = 255 - j + q0 + quad * 8;
                    int c = s0 & 7;
                    f16x8 bf = *(const f16x8*)&Ry[c * RSTRIDE + (s0 - c)];
                    acc[c8] = __builtin_amdgcn_mfma_f32_16x16x32_f16(
                        af, bf, acc[c8], 0, 0, 0);
                }
            }
        }

        // write M to LDS: (jl, p) at tmp[jl*256 + (p ^ ((jl&7)<<3))]
#pragma unroll
        for (int c8 = 0; c8 < 16; ++c8) {
            int jl = c8 * 16 + ln;
            int pb = wave * 16 + quad * 4;
            f32x4 a = acc[c8];
            f16x4 v;
            v[0] = (f16)a[0]; v[1] = (f16)a[1];
            v[2] = (f16)a[2]; v[3] = (f16)a[3];
            *(f16x4*)&tmp[jl * 256 + (pb ^ ((jl & 7) << 3))] = v;
        }
    }

    build_R<1024>(Rx, hxT + d * 256, tid);
#pragma unroll
    for (int a = 0; a < 16; ++a) acc[a] = (f32x4){0.f, 0.f, 0.f, 0.f};

    __syncthreads();   // tmp + Rx ready

    // ---------------- Phase 2: D[jl][i], waves = 4(igrp) x 4(jgrp) ---------
    const int igrp = wave & 3;
    const int jgrp = wave >> 2;
    const int nst = (igrp + 1) * 2;          // causal p-step bound
    for (int s = 0; s < nst; ++s) {
        const int p0 = s * 32;
        f16x8 af[4];
#pragma unroll
        for (int rt = 0; rt < 4; ++rt) {          // A = tmp[jl][p]
            int jl = jgrp * 64 + rt * 16 + ln;
            int off = (p0 + quad * 8) ^ ((jl & 7) << 3);
            af[rt] = *(const f16x8*)&tmp[jl * 256 + off];
        }
#pragma unroll
        for (int ct = 0; ct < 4; ++ct) {          // B[p][i] = hx[i-p]
            if (p0 <= igrp * 64 + ct * 16 + 15) { // wave-uniform causal skip
                int i = igrp * 64 + ct * 16 + ln;
                int s0 = 255 - i + p0 + quad * 8;
                int c = s0 & 7;
                f16x8 bf = *(const f16x8*)&Rx[c * RSTRIDE + (s0 - c)];
#pragma unroll
                for (int rt = 0; rt < 4; ++rt)
                    acc[rt * 4 + ct] = __builtin_amdgcn_mfma_f32_16x16x32_f16(
                        af[rt], bf, acc[rt * 4 + ct], 0, 0, 0);
            }
        }
    }

    // epilogue: out[i][j..j+3] = acc/512 + x*bias  (float4, coalesced)
    const float bv = bias[d];
    const float sc = 1.0f / 512.0f;
    float* obd = out + (size_t)bd * (SL * SL);
#pragma unroll
    for (int rt = 0; rt < 4; ++rt)
#pragma unroll
        for (int ct = 0; ct < 4; ++ct) {
            int i = igrp * 64 + ct * 16 + ln;
            int j = jgrp * 64 + rt * 16 + quad * 4;
            f32x4 a = acc[rt * 4 + ct];
            float4 xv = *(const float4*)(xbd + i * SL + j);
            float4 o;
            o.x = a[0] * sc + xv.x * bv;
            o.y = a[1] * sc + xv.y * bv;
            o.z = a[2] * sc + xv.z * bv;
            o.w = a[3] * sc + xv.w * bv;
            *(float4*)(obd + i * SL + j) = o;
        }
}

// ---------------------------------------------------------------------------
// Phase 1 for the FALLBACK j-split kernel (templated on J0).
// ---------------------------------------------------------------------------
template<int J0>
__device__ __forceinline__ void phase1(
    const float* __restrict__ xr0, const float* __restrict__ xr1,
    const f16* __restrict__ R, f32x4 (&acc)[16], int ln, int quad)
{
    constexpr int QS = (J0 == 0) ? 4 : 8;   // q < J0+128 needed
    float4 a0 = *(const float4*)xr0;
    float4 a1 = *(const float4*)(xr0 + 4);
    float4 b0 = *(const float4*)xr1;
    float4 b1 = *(const float4*)(xr1 + 4);

#pragma unroll
    for (int s = 0; s < QS; ++s) {
        const int q0 = s * 32;
        f16x8 af0 = cvt8(a0, a1);
        f16x8 af1 = cvt8(b0, b1);
        if (s + 1 < QS) {
            a0 = *(const float4*)(xr0 + q0 + 32);
            a1 = *(const float4*)(xr0 + q0 + 36);
            b0 = *(const float4*)(xr1 + q0 + 32);
            b1 = *(const float4*)(xr1 + q0 + 36);
        }
#pragma unroll
        for (int c8 = 0; c8 < 8; ++c8) {
            if (32 * s <= J0 + c8 * 16 + 15) {     // compile-time fold
                int j = J0 + c8 * 16 + ln;
                int s0 = 255 - j + q0 + quad * 8;
                int c = s0 & 7;
                f16x8 bf = *(const f16x8*)&R[c * RSTRIDE + (s0 - c)];
                acc[c8] = __builtin_amdgcn_mfma_f32_16x16x32_f16(
                    af0, bf, acc[c8], 0, 0, 0);
                acc[8 + c8] = __builtin_amdgcn_mfma_f32_16x16x32_f16(
                    af1, bf, acc[8 + c8], 0, 0, 0);
            }
        }
    }
}

// ---------------------------------------------------------------------------
// FALLBACK: the round-2 fused j-split kernel (proven 46.3 us) in case the
// dynamic-LDS attribute can't be set.
// ---------------------------------------------------------------------------
__global__ __launch_bounds__(512, 4) void k_fused(
    const float* __restrict__ x, const f16* __restrict__ hxT,
    const f16* __restrict__ hyT, const float* __restrict__ bias,
    float* __restrict__ out)
{
    const int bd = blockIdx.x & 255;
    const int j0 = (blockIdx.x >> 8) << 7;
    const int d  = bd & 63;
    const int tid  = threadIdx.x;
    const int lane = tid & 63;
    const int wave = tid >> 6;
    const int ln   = lane & 15;
    const int quad = lane >> 4;

    __shared__ __align__(16) f16 tmp[128 * 256];   // [jl][p ^ ((jl&7)<<3)]
    __shared__ __align__(16) f16 R[8 * RSTRIDE];

    const float* xbd = x + (size_t)bd * (SL * SL);

    build_R<512>(R, hyT + d * 256, tid);

    f32x4 acc[16];
#pragma unroll
    for (int a = 0; a < 16; ++a) acc[a] = (f32x4){0.f, 0.f, 0.f, 0.f};

    __syncthreads();   // R(hy) ready

    {
        const float* xr0 = xbd + (wave * 32 + ln) * SL + quad * 8;
        const float* xr1 = xr0 + 16 * SL;
        if (j0 == 0) phase1<0>(xr0, xr1, R, acc, ln, quad);
        else         phase1<128>(xr0, xr1, R, acc, ln, quad);

#pragma unroll
        for (int r = 0; r < 2; ++r)
#pragma unroll
            for (int c8 = 0; c8 < 8; ++c8) {
                int jl = c8 * 16 + ln;
                int pb = wave * 32 + r * 16 + quad * 4;
                f32x4 a = acc[r * 8 + c8];
                f16x4 v;
                v[0] = (f16)a[0]; v[1] = (f16)a[1];
                v[2] = (f16)a[2]; v[3] = (f16)a[3];
                *(f16x4*)&tmp[jl * 256 + (pb ^ ((jl & 7) << 3))] = v;
            }
    }

    __syncthreads();   // tmp complete, R(hy) reads done
    build_R<512>(R, hxT + d * 256, tid);
#pragma unroll
    for (int a = 0; a < 16; ++a) acc[a] = (f32x4){0.f, 0.f, 0.f, 0.f};
    __syncthreads();   // R(hx) ready

    const int igrp = wave & 3;
    const int jgrp = wave >> 2;
    const int nst = (igrp + 1) * 2;
    for (int s = 0; s < nst; ++s) {
        const int p0 = s * 32;
        f16x8 af[4];
#pragma unroll
        for (int rt = 0; rt < 4; ++rt) {
            int jl = jgrp * 64 + rt * 16 + ln;
            int off = (p0 + quad * 8) ^ ((jl & 7) << 3);
            af[rt] = *(const f16x8*)&tmp[jl * 256 + off];
        }
#pragma unroll
        for (int ct = 0; ct < 4; ++ct) {
            if (p0 <= igrp * 64 + ct * 16 + 15) {
                int i = igrp * 64 + ct * 16 + ln;
                int s0 = 255 - i + p0 + quad * 8;
                int c = s0 & 7;
                f16x8 bf = *(const f16x8*)&R[c * RSTRIDE + (s0 - c)];
#pragma unroll
                for (int rt = 0; rt < 4; ++rt)
                    acc[rt * 4 + ct] = __builtin_amdgcn_mfma_f32_16x16x32_f16(
                        af[rt], bf, acc[rt * 4 + ct], 0, 0, 0);
            }
        }
    }

    const float bv = bias[d];
    const float sc = 1.0f / 512.0f;
    float* obd = out + (size_t)bd * (SL * SL);
#pragma unroll
    for (int rt = 0; rt < 4; ++rt)
#pragma unroll
        for (int ct = 0; ct < 4; ++ct) {
            int i = igrp * 64 + ct * 16 + ln;
            int j = j0 + jgrp * 64 + rt * 16 + quad * 4;
            f32x4 a = acc[rt * 4 + ct];
            float4 xv = *(const float4*)(xbd + i * SL + j);
            float4 o;
            o.x = a[0] * sc + xv.x * bv;
            o.y = a[1] * sc + xv.y * bv;
            o.z = a[2] * sc + xv.z * bv;
            o.w = a[3] * sc + xv.w * bv;
            *(float4*)(obd + i * SL + j) = o;
        }
}

extern "C" void kernel_launch(void* const* d_in, const int* in_sizes, int n_in,
                              void* d_out, int out_size, void* d_ws, size_t ws_size,
                              hipStream_t stream)
{
    (void)in_sizes; (void)n_in; (void)out_size; (void)ws_size;
    const float* x     = (const float*)d_in[0];
    const float* z     = (const float*)d_in[1];
    const float* Xw1   = (const float*)d_in[2];
    const float* Xb1   = (const float*)d_in[3];
    const float* Xw2   = (const float*)d_in[4];
    const float* Xb2   = (const float*)d_in[5];
    const float* Xw3   = (const float*)d_in[6];
    const float* Xb3   = (const float*)d_in[7];
    const float* Xwo   = (const float*)d_in[8];
    const float* Xfreq = (const float*)d_in[9];
    const float* Yw1   = (const float*)d_in[10];
    const float* Yb1   = (const float*)d_in[11];
    const float* Yw2   = (const float*)d_in[12];
    const float* Yb2   = (const float*)d_in[13];
    const float* Yw3   = (const float*)d_in[14];
    const float* Yb3   = (const float*)d_in[15];
    const float* Ywo   = (const float*)d_in[16];
    const float* Yfreq = (const float*)d_in[17];
    const float* bias  = (const float*)d_in[18];

    f16* hxT = (f16*)d_ws;                 // [64][256] f16
    f16* hyT = hxT + 64 * 256;             // [64][256] f16

    k_filters<<<dim3(256, 2), 64, 0, stream>>>(
        z, Xw1, Xb1, Xw2, Xb2, Xw3, Xb3, Xwo, Xfreq,
        Yw1, Yb1, Yw2, Yb2, Yw3, Yb3, Ywo, Yfreq, hxT, hyT);

    const int dyn_lds = (256 * 256 + 2 * 8 * RSTRIDE) * (int)sizeof(f16); // 141056
    static hipError_t attr_rc = hipFuncSetAttribute(
        (const void*)k_one, hipFuncAttributeMaxDynamicSharedMemorySize, dyn_lds);

    if (attr_rc == hipSuccess) {
        k_one<<<256, 1024, dyn_lds, stream>>>(x, hxT, hyT, bias, (float*)d_out);
    } else {
        k_fused<<<512, 512, 0, stream>>>(x, hxT, hyT, bias, (float*)d_out);
    }
}